// Round 10
// baseline (253.150 us; speedup 1.0000x reference)
//
#include <hip/hip_runtime.h>
#include <hip/hip_bf16.h>
#include <stdint.h>

#define ALPHA_ 0.2f
#define EPS_   1e-6f

typedef __attribute__((ext_vector_type(8))) short  short8;
typedef __attribute__((ext_vector_type(4))) float  float4v;

static __device__ __forceinline__ unsigned short f2bf(float x) {
    union { float f; unsigned int u; } c; c.f = x;
    return (unsigned short)((c.u + 0x7fffu + ((c.u >> 16) & 1u)) >> 16);
}

// ---------------- K0: WT in MFMA-B-fragment order (for k_wh) ----------------
__global__ __launch_bounds__(256) void k_wt(const float* __restrict__ W,
                                            unsigned short* __restrict__ WTs) {
    const int g  = blockIdx.x * 256 + threadIdx.x;   // 8192 threads
    const int fb = g >> 9, kc = (g >> 6) & 7, l = g & 63;
    const int m = l & 15, quad = l >> 4;
    const int f = fb * 16 + m, d0 = kc * 32 + quad * 8;
    unsigned short v[8];
#pragma unroll
    for (int i = 0; i < 8; ++i) v[i] = f2bf(W[(d0 + i) * 256 + f]);
    uint4 o;
    o.x = (unsigned)v[0] | ((unsigned)v[1] << 16);
    o.y = (unsigned)v[2] | ((unsigned)v[3] << 16);
    o.z = (unsigned)v[4] | ((unsigned)v[5] << 16);
    o.w = (unsigned)v[6] | ((unsigned)v[7] << 16);
    *(uint4*)(WTs + (size_t)g * 8) = o;
}

// ---------------- K1: MFMA Wh = h@W; fused s1/s2; WhS in B-frag order -------
__global__ __launch_bounds__(512) void k_wh(const float* __restrict__ h,
                                            const unsigned short* __restrict__ WTs,
                                            const float* __restrict__ a,
                                            unsigned short* __restrict__ WhS,
                                            float* __restrict__ s1g,
                                            float* __restrict__ s2g) {
    __shared__ __align__(16) unsigned short A_lds[32][264];   // pad 256->264
    __shared__ __align__(16) unsigned short T_lds[256][40];   // [f][j] pad 32->40
    __shared__ float s1p[32], s2p[32];
    const int t    = threadIdx.x;
    const int lane = t & 63;
    const int wv   = t >> 6;              // 0..7
    const int m    = lane & 15;
    const int quad = lane >> 4;
    const int r0   = blockIdx.x * 32;     // 512 blocks
    const int b    = blockIdx.x >> 6;
    const int jc   = blockIdx.x & 63;
    const int j0   = r0 & 2047;

    if (t < 32) { s1p[t] = 0.f; s2p[t] = 0.f; }

    // stage h tile fp32 -> bf16 LDS (coalesced float4)
#pragma unroll
    for (int k = 0; k < 4; ++k) {
        const int flat = t + k * 512;
        const int r  = flat >> 6;
        const int d4 = flat & 63;
        float4v hv = *(const float4v*)(h + (size_t)(r0 + r) * 256 + d4 * 4);
        uint2 pk;
        pk.x = (unsigned)f2bf(hv.x) | ((unsigned)f2bf(hv.y) << 16);
        pk.y = (unsigned)f2bf(hv.z) | ((unsigned)f2bf(hv.w) << 16);
        *(uint2*)&A_lds[r][d4 * 4] = pk;
    }
    __syncthreads();

    const int fbase = wv * 32;
    float4v acc[2][2];
#pragma unroll
    for (int it = 0; it < 2; ++it)
#pragma unroll
        for (int ft = 0; ft < 2; ++ft)
#pragma unroll
            for (int r = 0; r < 4; ++r) acc[it][ft][r] = 0.f;

    const unsigned short* wtb = WTs + (size_t)(wv * 2) * 4096 + lane * 8;

#pragma unroll
    for (int kc = 0; kc < 8; ++kc) {
        short8 af0 = *(const short8*)&A_lds[m][kc * 32 + quad * 8];
        short8 af1 = *(const short8*)&A_lds[16 + m][kc * 32 + quad * 8];
#pragma unroll
        for (int ft = 0; ft < 2; ++ft) {
            short8 bf = *(const short8*)(wtb + (size_t)ft * 4096 + kc * 512);
            acc[0][ft] = __builtin_amdgcn_mfma_f32_16x16x32_bf16(af0, bf, acc[0][ft], 0, 0, 0);
            acc[1][ft] = __builtin_amdgcn_mfma_f32_16x16x32_bf16(af1, bf, acc[1][ft], 0, 0, 0);
        }
    }

    // fused s1/s2
    float a1v[2], a2v[2];
#pragma unroll
    for (int ft = 0; ft < 2; ++ft) {
        a1v[ft] = a[fbase + ft * 16 + m];
        a2v[ft] = a[256 + fbase + ft * 16 + m];
    }
#pragma unroll
    for (int it = 0; it < 2; ++it) {
#pragma unroll
        for (int reg = 0; reg < 4; ++reg) {
            float v1 = 0.f, v2 = 0.f;
#pragma unroll
            for (int ft = 0; ft < 2; ++ft) {
                const float c = acc[it][ft][reg];
                v1 = fmaf(c, a1v[ft], v1);
                v2 = fmaf(c, a2v[ft], v2);
            }
            v1 += __shfl_xor(v1, 1); v2 += __shfl_xor(v2, 1);
            v1 += __shfl_xor(v1, 2); v2 += __shfl_xor(v2, 2);
            v1 += __shfl_xor(v1, 4); v2 += __shfl_xor(v2, 4);
            v1 += __shfl_xor(v1, 8); v2 += __shfl_xor(v2, 8);
            if (m == 0) {
                const int row = it * 16 + quad * 4 + reg;
                atomicAdd(&s1p[row], v1);
                atomicAdd(&s2p[row], v2);
            }
        }
    }

    // C -> T_lds[f][j]
#pragma unroll
    for (int it = 0; it < 2; ++it)
#pragma unroll
        for (int ft = 0; ft < 2; ++ft)
#pragma unroll
            for (int reg = 0; reg < 4; ++reg)
                T_lds[fbase + ft * 16 + m][it * 16 + quad * 4 + reg] =
                    f2bf(acc[it][ft][reg]);

    __syncthreads();   // cross-wave T_lds reads below

    // swizzled store: WhS[(b*64+jc)*16 + fb][l] = T_lds[fb*16 + (l&15)][(l>>4)*8 ..+8]
#pragma unroll
    for (int e = 0; e < 2; ++e) {
        const int idx = e * 512 + t;
        const int fb = idx >> 6, l = idx & 63;
        uint4 v = *(const uint4*)&T_lds[fb * 16 + (l & 15)][(l >> 4) * 8];
        *(uint4*)(WhS + ((size_t)(b * 64 + jc) * 16 + fb) * 512 + l * 8) = v;
    }

    if (t < 32) {
        s1g[(size_t)b * 2048 + j0 + t] = s1p[t];
        s2g[(size_t)b * 2048 + j0 + t] = s2p[t];
    }
}

// ---------------- K3: R9 + LDS-only barrier + B-in-regs (counted vmcnt) -----
// R9 (231.8 total, k_attn ~67): covered adj prefetch worked. Remaining:
// (1) __syncthreads' vmcnt(0) caps adj cover at the P phase (~500cy < 900
//     HBM); (2) B loaded at point of use -> every MFMA phase head eats
//     ~300cy L2 latency; HBM/L2 idle during P. Fix = T3/T4 mechanism:
//  - in-loop barrier is now `s_waitcnt lgkmcnt(0); s_barrier` (LDS-only).
//    Correctness: each wave's lgkmcnt(0) covers its OWN pbuf ds_writes and
//    ds_reads; barrier arrival of all waves preserves the pbuf WAR distance
//    (write pbuf[x] is 1 barrier after the last read of pbuf[x], and readers
//    hold data in regs before arriving). Global loads now FLY ACROSS.
//  - per step, issue order: B[s]->regs FIRST, then adj[s+1] (sched_barrier
//    pins both above P). FIFO counted vmcnt: MFMA waits B with vmcnt(2)
//    (adj stays in flight); P(s+1) waits adj with B[s+1]/adj[s+2] behind it.
//    Cover: B ~= P phase (500 >= 300 L2); adj ~= P+bar+MFMA (~900 = HBM).
//  - single B reg set (32 VGPR), reloaded per step after its MFMA use.
static __device__ __forceinline__ unsigned pk2bf(float lo, float hi) {
    float2 v; v.x = lo; v.y = hi;
    union { __hip_bfloat162 h2; unsigned u; } cv;
    cv.h2 = __float22bfloat162_rn(v);
    return cv.u;
}

static __device__ __forceinline__ uint2 pquad(float4v av, float4v s2v,
                                              float s1, float& rs) {
    float e0 = s1 + s2v.x, e1 = s1 + s2v.y, e2 = s1 + s2v.z, e3 = s1 + s2v.w;
    e0 = fmaxf(e0, ALPHA_ * e0); e1 = fmaxf(e1, ALPHA_ * e1);
    e2 = fmaxf(e2, ALPHA_ * e2); e3 = fmaxf(e3, ALPHA_ * e3);
    const float p0 = (av.x + EPS_) * __expf(e0);
    const float p1 = (av.y + EPS_) * __expf(e1);
    const float p2 = (av.z + EPS_) * __expf(e2);
    const float p3 = (av.w + EPS_) * __expf(e3);
    rs += (p0 + p1) + (p2 + p3);
    uint2 r;
    r.x = pk2bf(p0, p1);
    r.y = pk2bf(p2, p3);
    return r;
}

__global__ __launch_bounds__(512, 4) void k_attn(const float* __restrict__ adj,
                                                 const unsigned short* __restrict__ WhS,
                                                 const float* __restrict__ s1g,
                                                 const float* __restrict__ s2g,
                                                 float* __restrict__ out) {
    __shared__ __align__(16) unsigned short pbuf[2][32][140];  // pad 128->140
    __shared__ __align__(16) float s2_lds[2048];               // whole s2 row of b
    __shared__ float rsum_lds[32];

    const int t    = threadIdx.x;
    const int lane = t & 63;
    const int wv   = t >> 6;             // 0..7
    const int m    = lane & 15;
    const int quad = lane >> 4;
    const int blk  = blockIdx.x;
    const int b    = blk & 7;            // XCD-pinned batch
    const int i0   = (blk >> 3) * 32;    // 64 i-tiles of 32 rows

    const int ip = t >> 4;               // 0..31  (i-row)
    const int jq = t & 15;               // 0..15  (8 j each)

    const float* adjp = adj + (size_t)(b * 2048 + i0 + ip) * 2048 + jq * 8;
    const float  s1v  = s1g[(size_t)b * 2048 + i0 + ip];

    const int fbb = wv * 2;              // this wave's first f-block (of 16)
    const unsigned short* whs = WhS + (size_t)b * 64 * 16 * 512 + lane * 8;

    // stage s2 once (8KB; P-phase reads become broadcast ds_read)
    *(float4v*)&s2_lds[t * 4] = *(const float4v*)(s2g + (size_t)b * 2048 + t * 4);

    float4v acc[2][2];   // [it][ft]
#pragma unroll
    for (int it = 0; it < 2; ++it)
#pragma unroll
        for (int ft = 0; ft < 2; ++ft)
#pragma unroll
            for (int r = 0; r < 4; ++r) acc[it][ft][r] = 0.f;

    float rs = 0.f;

    // prologue: step-0 adj into bufA
    float4v adjA[2], adjB[2];
    adjA[0] = *(const float4v*)(adjp);
    adjA[1] = *(const float4v*)(adjp + 4);

    __syncthreads();   // s2_lds visible (full drain ONCE; adjA consumed next)

    short8 breg[8];    // B[s] fragments: [kc*2 + which], reloaded each step

#define ISSUE_B(sp)                                                             \
    {                                                                           \
        _Pragma("unroll")                                                       \
        for (int kc = 0; kc < 4; ++kc) {                                        \
            const unsigned short* bp =                                          \
                whs + ((size_t)(((sp) * 4 + kc) * 16 + fbb)) * 512;             \
            breg[kc * 2]     = *(const short8*)bp;                              \
            breg[kc * 2 + 1] = *(const short8*)(bp + 512);                      \
        }                                                                       \
    }

#define ISSUE_ADJ(ns, dst)                                                      \
    {                                                                           \
        dst[0] = *(const float4v*)(adjp + (size_t)(ns) * 128);                  \
        dst[1] = *(const float4v*)(adjp + (size_t)(ns) * 128 + 4);              \
    }

#define PHASE_P(sp, src, buf)                                                   \
    {                                                                           \
        _Pragma("unroll")                                                       \
        for (int c = 0; c < 2; ++c) {                                           \
            float4v s2v = *(const float4v*)&s2_lds[(sp) * 128 + jq * 8 + c * 4];\
            uint2 pk = pquad(src[c], s2v, s1v, rs);                             \
            *(uint2*)&pbuf[buf][ip][jq * 8 + c * 4] = pk;                       \
        }                                                                       \
    }

// LDS-only barrier: pbuf visibility needs lgkmcnt(0) of each wave's own
// ds ops; global loads stay in flight across (counted vmcnt at use).
#define LDS_BARRIER()                                                           \
    asm volatile("s_waitcnt lgkmcnt(0)" ::: "memory");                          \
    __builtin_amdgcn_s_barrier();                                               \
    __builtin_amdgcn_sched_barrier(0);

#define PHASE_MFMA(buf)                                                         \
    {                                                                           \
        _Pragma("unroll")                                                       \
        for (int kc = 0; kc < 4; ++kc) {                                        \
            short8 af0 = *(const short8*)&pbuf[buf][m][kc * 32 + quad * 8];     \
            short8 af1 = *(const short8*)&pbuf[buf][16 + m][kc * 32 + quad * 8];\
            acc[0][0] = __builtin_amdgcn_mfma_f32_16x16x32_bf16(af0, breg[kc*2],   acc[0][0], 0, 0, 0); \
            acc[0][1] = __builtin_amdgcn_mfma_f32_16x16x32_bf16(af0, breg[kc*2+1], acc[0][1], 0, 0, 0); \
            acc[1][0] = __builtin_amdgcn_mfma_f32_16x16x32_bf16(af1, breg[kc*2],   acc[1][0], 0, 0, 0); \
            acc[1][1] = __builtin_amdgcn_mfma_f32_16x16x32_bf16(af1, breg[kc*2+1], acc[1][1], 0, 0, 0); \
        }                                                                       \
    }

    for (int s = 0; s < 16; s += 2) {
        // ---- even step s: issue B[s] FIRST, then adj[s+1]; pin above P ----
        ISSUE_B(s)
        ISSUE_ADJ(s + 1, adjB)                  // s+1 <= 15: never wraps
        __builtin_amdgcn_sched_barrier(0);
        PHASE_P(s, adjA, 0)
        LDS_BARRIER()
        PHASE_MFMA(0)                           // B wait = vmcnt(2): adj flies on

        // ---- odd step s+1 ----
        ISSUE_B(s + 1)
        ISSUE_ADJ((s + 2) & 15, adjA)           // wraps only at s=14 (reload)
        __builtin_amdgcn_sched_barrier(0);
        PHASE_P(s + 1, adjB, 1)
        LDS_BARRIER()
        PHASE_MFMA(1)
    }

#undef ISSUE_B
#undef ISSUE_ADJ
#undef PHASE_P
#undef LDS_BARRIER
#undef PHASE_MFMA

    // rowsum: lanes xor 1,2,4,8 share ip (t = ip*16 + jq)
    rs += __shfl_xor(rs, 1);
    rs += __shfl_xor(rs, 2);
    rs += __shfl_xor(rs, 4);
    rs += __shfl_xor(rs, 8);
    if (jq == 0) rsum_lds[ip] = rs;
    __syncthreads();

    // epilogue: C/D col = lane&15 (f), row = quad*4+reg (i), +16 per it
#pragma unroll
    for (int reg = 0; reg < 4; ++reg) {
        const int row  = quad * 4 + reg;
        const float i0v = 1.0f / rsum_lds[row];
        const float i1v = 1.0f / rsum_lds[16 + row];
#pragma unroll
        for (int ft = 0; ft < 2; ++ft) {
            const int f = wv * 32 + ft * 16 + m;
            out[(size_t)(b * 2048 + i0 + row) * 256 + f]      = acc[0][ft][reg] * i0v;
            out[(size_t)(b * 2048 + i0 + 16 + row) * 256 + f] = acc[1][ft][reg] * i1v;
        }
    }
}

extern "C" void kernel_launch(void* const* d_in, const int* in_sizes, int n_in,
                              void* d_out, int out_size, void* d_ws, size_t ws_size,
                              hipStream_t stream) {
    const float* h   = (const float*)d_in[0];   // (8,2048,256)
    const float* adj = (const float*)d_in[1];   // (8,2048,2048)
    const float* W   = (const float*)d_in[2];   // (256,256)
    const float* a   = (const float*)d_in[3];   // (512,1)
    float* out = (float*)d_out;                 // (8,2048,256)

    unsigned short* WhS = (unsigned short*)d_ws;                        // 8.4 MB
    unsigned short* WTs = (unsigned short*)((char*)d_ws + 8388608);     // 128 KB
    float*          s1  = (float*)((char*)d_ws + 8388608 + 131072);     // 64 KB
    float*          s2  = s1 + 16384;                                   // 64 KB

    k_wt  <<<dim3(32),   dim3(256), 0, stream>>>(W, WTs);
    k_wh  <<<dim3(512),  dim3(512), 0, stream>>>(h, WTs, a, WhS, s1, s2);
    k_attn<<<dim3(512),  dim3(512), 0, stream>>>(adj, WhS, s1, s2, out);
}

// Round 11
// 229.346 us; speedup vs baseline: 1.1038x; 1.1038x over previous
//
#include <hip/hip_runtime.h>
#include <hip/hip_bf16.h>
#include <stdint.h>

#define ALPHA_ 0.2f
#define EPS_   1e-6f

typedef __attribute__((ext_vector_type(8))) short  short8;
typedef __attribute__((ext_vector_type(4))) float  float4v;

static __device__ __forceinline__ unsigned short f2bf(float x) {
    union { float f; unsigned int u; } c; c.f = x;
    return (unsigned short)((c.u + 0x7fffu + ((c.u >> 16) & 1u)) >> 16);
}

// ---------------- K0: WT in MFMA-B-fragment order (for k_wh) ----------------
__global__ __launch_bounds__(256) void k_wt(const float* __restrict__ W,
                                            unsigned short* __restrict__ WTs) {
    const int g  = blockIdx.x * 256 + threadIdx.x;   // 8192 threads
    const int fb = g >> 9, kc = (g >> 6) & 7, l = g & 63;
    const int m = l & 15, quad = l >> 4;
    const int f = fb * 16 + m, d0 = kc * 32 + quad * 8;
    unsigned short v[8];
#pragma unroll
    for (int i = 0; i < 8; ++i) v[i] = f2bf(W[(d0 + i) * 256 + f]);
    uint4 o;
    o.x = (unsigned)v[0] | ((unsigned)v[1] << 16);
    o.y = (unsigned)v[2] | ((unsigned)v[3] << 16);
    o.z = (unsigned)v[4] | ((unsigned)v[5] << 16);
    o.w = (unsigned)v[6] | ((unsigned)v[7] << 16);
    *(uint4*)(WTs + (size_t)g * 8) = o;
}

// ---------------- K1: MFMA Wh = h@W; fused s1/s2; WhS in B-frag order -------
__global__ __launch_bounds__(512) void k_wh(const float* __restrict__ h,
                                            const unsigned short* __restrict__ WTs,
                                            const float* __restrict__ a,
                                            unsigned short* __restrict__ WhS,
                                            float* __restrict__ s1g,
                                            float* __restrict__ s2g) {
    __shared__ __align__(16) unsigned short A_lds[32][264];   // pad 256->264
    __shared__ __align__(16) unsigned short T_lds[256][40];   // [f][j] pad 32->40
    __shared__ float s1p[32], s2p[32];
    const int t    = threadIdx.x;
    const int lane = t & 63;
    const int wv   = t >> 6;              // 0..7
    const int m    = lane & 15;
    const int quad = lane >> 4;
    const int r0   = blockIdx.x * 32;     // 512 blocks
    const int b    = blockIdx.x >> 6;
    const int jc   = blockIdx.x & 63;
    const int j0   = r0 & 2047;

    if (t < 32) { s1p[t] = 0.f; s2p[t] = 0.f; }

    // stage h tile fp32 -> bf16 LDS (coalesced float4)
#pragma unroll
    for (int k = 0; k < 4; ++k) {
        const int flat = t + k * 512;
        const int r  = flat >> 6;
        const int d4 = flat & 63;
        float4v hv = *(const float4v*)(h + (size_t)(r0 + r) * 256 + d4 * 4);
        uint2 pk;
        pk.x = (unsigned)f2bf(hv.x) | ((unsigned)f2bf(hv.y) << 16);
        pk.y = (unsigned)f2bf(hv.z) | ((unsigned)f2bf(hv.w) << 16);
        *(uint2*)&A_lds[r][d4 * 4] = pk;
    }
    __syncthreads();

    const int fbase = wv * 32;
    float4v acc[2][2];
#pragma unroll
    for (int it = 0; it < 2; ++it)
#pragma unroll
        for (int ft = 0; ft < 2; ++ft)
#pragma unroll
            for (int r = 0; r < 4; ++r) acc[it][ft][r] = 0.f;

    const unsigned short* wtb = WTs + (size_t)(wv * 2) * 4096 + lane * 8;

#pragma unroll
    for (int kc = 0; kc < 8; ++kc) {
        short8 af0 = *(const short8*)&A_lds[m][kc * 32 + quad * 8];
        short8 af1 = *(const short8*)&A_lds[16 + m][kc * 32 + quad * 8];
#pragma unroll
        for (int ft = 0; ft < 2; ++ft) {
            short8 bf = *(const short8*)(wtb + (size_t)ft * 4096 + kc * 512);
            acc[0][ft] = __builtin_amdgcn_mfma_f32_16x16x32_bf16(af0, bf, acc[0][ft], 0, 0, 0);
            acc[1][ft] = __builtin_amdgcn_mfma_f32_16x16x32_bf16(af1, bf, acc[1][ft], 0, 0, 0);
        }
    }

    // fused s1/s2
    float a1v[2], a2v[2];
#pragma unroll
    for (int ft = 0; ft < 2; ++ft) {
        a1v[ft] = a[fbase + ft * 16 + m];
        a2v[ft] = a[256 + fbase + ft * 16 + m];
    }
#pragma unroll
    for (int it = 0; it < 2; ++it) {
#pragma unroll
        for (int reg = 0; reg < 4; ++reg) {
            float v1 = 0.f, v2 = 0.f;
#pragma unroll
            for (int ft = 0; ft < 2; ++ft) {
                const float c = acc[it][ft][reg];
                v1 = fmaf(c, a1v[ft], v1);
                v2 = fmaf(c, a2v[ft], v2);
            }
            v1 += __shfl_xor(v1, 1); v2 += __shfl_xor(v2, 1);
            v1 += __shfl_xor(v1, 2); v2 += __shfl_xor(v2, 2);
            v1 += __shfl_xor(v1, 4); v2 += __shfl_xor(v2, 4);
            v1 += __shfl_xor(v1, 8); v2 += __shfl_xor(v2, 8);
            if (m == 0) {
                const int row = it * 16 + quad * 4 + reg;
                atomicAdd(&s1p[row], v1);
                atomicAdd(&s2p[row], v2);
            }
        }
    }

    // C -> T_lds[f][j]
#pragma unroll
    for (int it = 0; it < 2; ++it)
#pragma unroll
        for (int ft = 0; ft < 2; ++ft)
#pragma unroll
            for (int reg = 0; reg < 4; ++reg)
                T_lds[fbase + ft * 16 + m][it * 16 + quad * 4 + reg] =
                    f2bf(acc[it][ft][reg]);

    __syncthreads();   // cross-wave T_lds reads below

    // swizzled store: WhS[(b*64+jc)*16 + fb][l] = T_lds[fb*16 + (l&15)][(l>>4)*8 ..+8]
#pragma unroll
    for (int e = 0; e < 2; ++e) {
        const int idx = e * 512 + t;
        const int fb = idx >> 6, l = idx & 63;
        uint4 v = *(const uint4*)&T_lds[fb * 16 + (l & 15)][(l >> 4) * 8];
        *(uint4*)(WhS + ((size_t)(b * 64 + jc) * 16 + fb) * 512 + l * 8) = v;
    }

    if (t < 32) {
        s1g[(size_t)b * 2048 + j0 + t] = s1p[t];
        s2g[(size_t)b * 2048 + j0 + t] = s2p[t];
    }
}

// ---------------- K3: R9 framework + stall-free MFMA (P/MFMA reorder) -------
// R10 (raw barriers + sched pinning) regressed 18us: defeated compiler
// scheduling (m141-class failure). This keeps R9's proven framework (plain
// __syncthreads, ONE sched_barrier(0) after the issue block) and gets
// R10's intended benefit via ordering only. Key: pbuf is double-buffered,
// so P(s+1) and MFMA(s) can both sit between the same barrier pair:
//   [bar] issue B(s)+adj(s+2) -> P(s+1) -> MFMA(s) [bar]
// - B's ~300cy L2 latency covered by P phase; waited with a COUNTED vmcnt
//   (adj issued after B in FIFO stays in flight).
// - MFMA runs entirely from registers (zero in-phase loads).
// - adj(s+2) has P+MFMA (~800cy) cover before the barrier drain (~100cy tail
//   vs HBM ~900cy), and P(s+1) reads adj from regs loaded LAST iteration.
// WAR: MFMA(s) reads pbuf[s&1] pre-barrier; next write of that buffer is
// P(s+2) post-barrier. Visibility: P(s+1) pre-barrier, MFMA(s+1) post. OK.
static __device__ __forceinline__ unsigned pk2bf(float lo, float hi) {
    float2 v; v.x = lo; v.y = hi;
    union { __hip_bfloat162 h2; unsigned u; } cv;
    cv.h2 = __float22bfloat162_rn(v);
    return cv.u;
}

static __device__ __forceinline__ uint2 pquad(float4v av, float4v s2v,
                                              float s1, float& rs) {
    float e0 = s1 + s2v.x, e1 = s1 + s2v.y, e2 = s1 + s2v.z, e3 = s1 + s2v.w;
    e0 = fmaxf(e0, ALPHA_ * e0); e1 = fmaxf(e1, ALPHA_ * e1);
    e2 = fmaxf(e2, ALPHA_ * e2); e3 = fmaxf(e3, ALPHA_ * e3);
    const float p0 = (av.x + EPS_) * __expf(e0);
    const float p1 = (av.y + EPS_) * __expf(e1);
    const float p2 = (av.z + EPS_) * __expf(e2);
    const float p3 = (av.w + EPS_) * __expf(e3);
    rs += (p0 + p1) + (p2 + p3);
    uint2 r;
    r.x = pk2bf(p0, p1);
    r.y = pk2bf(p2, p3);
    return r;
}

__global__ __launch_bounds__(512, 4) void k_attn(const float* __restrict__ adj,
                                                 const unsigned short* __restrict__ WhS,
                                                 const float* __restrict__ s1g,
                                                 const float* __restrict__ s2g,
                                                 float* __restrict__ out) {
    __shared__ __align__(16) unsigned short pbuf[2][32][140];  // pad 128->140
    __shared__ __align__(16) float s2_lds[2048];               // whole s2 row of b
    __shared__ float rsum_lds[32];

    const int t    = threadIdx.x;
    const int lane = t & 63;
    const int wv   = t >> 6;             // 0..7
    const int m    = lane & 15;
    const int quad = lane >> 4;
    const int blk  = blockIdx.x;
    const int b    = blk & 7;            // XCD-pinned batch
    const int i0   = (blk >> 3) * 32;    // 64 i-tiles of 32 rows

    const int ip = t >> 4;               // 0..31  (i-row)
    const int jq = t & 15;               // 0..15  (8 j each)

    const float* adjp = adj + (size_t)(b * 2048 + i0 + ip) * 2048 + jq * 8;
    const float  s1v  = s1g[(size_t)b * 2048 + i0 + ip];

    const int fbb = wv * 2;              // this wave's first f-block (of 16)
    const unsigned short* whs = WhS + (size_t)b * 64 * 16 * 512 + lane * 8;

    // stage s2 once (8KB; P-phase reads become broadcast ds_read)
    *(float4v*)&s2_lds[t * 4] = *(const float4v*)(s2g + (size_t)b * 2048 + t * 4);

    float4v acc[2][2];   // [it][ft]
#pragma unroll
    for (int it = 0; it < 2; ++it)
#pragma unroll
        for (int ft = 0; ft < 2; ++ft)
#pragma unroll
            for (int r = 0; r < 4; ++r) acc[it][ft][r] = 0.f;

    float rs = 0.f;

    short8 breg[8];      // B[s] fragments, single set (reloaded each step)
    float4v adjA[2], adjB[2], adj0[2];

#define ISSUE_B(sp)                                                             \
    {                                                                           \
        _Pragma("unroll")                                                       \
        for (int kc = 0; kc < 4; ++kc) {                                        \
            const unsigned short* bp =                                          \
                whs + ((size_t)(((sp) * 4 + kc) * 16 + fbb)) * 512;             \
            breg[kc * 2]     = *(const short8*)bp;                              \
            breg[kc * 2 + 1] = *(const short8*)(bp + 512);                      \
        }                                                                       \
    }

#define ISSUE_ADJ(ns, dst)                                                      \
    {                                                                           \
        dst[0] = *(const float4v*)(adjp + (size_t)(ns) * 128);                  \
        dst[1] = *(const float4v*)(adjp + (size_t)(ns) * 128 + 4);              \
    }

#define PHASE_P(sp, src, buf)                                                   \
    {                                                                           \
        _Pragma("unroll")                                                       \
        for (int c = 0; c < 2; ++c) {                                           \
            float4v s2v = *(const float4v*)&s2_lds[(sp) * 128 + jq * 8 + c * 4];\
            uint2 pk = pquad(src[c], s2v, s1v, rs);                             \
            *(uint2*)&pbuf[buf][ip][jq * 8 + c * 4] = pk;                       \
        }                                                                       \
    }

#define PHASE_MFMA(buf)                                                         \
    {                                                                           \
        _Pragma("unroll")                                                       \
        for (int kc = 0; kc < 4; ++kc) {                                        \
            short8 af0 = *(const short8*)&pbuf[buf][m][kc * 32 + quad * 8];     \
            short8 af1 = *(const short8*)&pbuf[buf][16 + m][kc * 32 + quad * 8];\
            acc[0][0] = __builtin_amdgcn_mfma_f32_16x16x32_bf16(af0, breg[kc*2],   acc[0][0], 0, 0, 0); \
            acc[0][1] = __builtin_amdgcn_mfma_f32_16x16x32_bf16(af0, breg[kc*2+1], acc[0][1], 0, 0, 0); \
            acc[1][0] = __builtin_amdgcn_mfma_f32_16x16x32_bf16(af1, breg[kc*2],   acc[1][0], 0, 0, 0); \
            acc[1][1] = __builtin_amdgcn_mfma_f32_16x16x32_bf16(af1, breg[kc*2+1], acc[1][1], 0, 0, 0); \
        }                                                                       \
    }

    // ---- prologue: establish {pbuf[0]=P(0), adjA=adj(1)} ----
    ISSUE_ADJ(0, adj0)
    __syncthreads();                       // s2_lds visible; drains adj(0)
    ISSUE_ADJ(1, adjA)                     // covered by P(0) below
    __builtin_amdgcn_sched_barrier(0);
    PHASE_P(0, adj0, 0)
    __syncthreads();                       // pbuf[0] visible; drains adj(1)

    for (int s = 0; s < 16; s += 2) {
        // ---- even step s: pbuf[0]=P(s) live, adjA=adj(s+1) in regs ----
        ISSUE_B(s)
        ISSUE_ADJ((s + 2) & 15, adjB)      // wraps only at s=14 (unused then)
        __builtin_amdgcn_sched_barrier(0); // pin issues above P
        PHASE_P(s + 1, adjA, 1)            // covers B's L2 latency
        PHASE_MFMA(0)                      // B in regs: counted vmcnt, no drain
        __syncthreads();                   // drain tail ~100cy (adj had P+MFMA cover)

        // ---- odd step s+1: pbuf[1]=P(s+1) live, adjB=adj(s+2) in regs ----
        ISSUE_B(s + 1)
        ISSUE_ADJ((s + 3) & 15, adjA)      // wraps only at s=14 (unused then)
        __builtin_amdgcn_sched_barrier(0);
        if (s < 14) PHASE_P(s + 2, adjB, 0)  // P(16) doesn't exist (guard rs)
        PHASE_MFMA(1)
        __syncthreads();
    }

#undef ISSUE_B
#undef ISSUE_ADJ
#undef PHASE_P
#undef PHASE_MFMA

    // rowsum: lanes xor 1,2,4,8 share ip (t = ip*16 + jq)
    rs += __shfl_xor(rs, 1);
    rs += __shfl_xor(rs, 2);
    rs += __shfl_xor(rs, 4);
    rs += __shfl_xor(rs, 8);
    if (jq == 0) rsum_lds[ip] = rs;
    __syncthreads();

    // epilogue: C/D col = lane&15 (f), row = quad*4+reg (i), +16 per it
#pragma unroll
    for (int reg = 0; reg < 4; ++reg) {
        const int row  = quad * 4 + reg;
        const float i0v = 1.0f / rsum_lds[row];
        const float i1v = 1.0f / rsum_lds[16 + row];
#pragma unroll
        for (int ft = 0; ft < 2; ++ft) {
            const int f = wv * 32 + ft * 16 + m;
            out[(size_t)(b * 2048 + i0 + row) * 256 + f]      = acc[0][ft][reg] * i0v;
            out[(size_t)(b * 2048 + i0 + 16 + row) * 256 + f] = acc[1][ft][reg] * i1v;
        }
    }
}

extern "C" void kernel_launch(void* const* d_in, const int* in_sizes, int n_in,
                              void* d_out, int out_size, void* d_ws, size_t ws_size,
                              hipStream_t stream) {
    const float* h   = (const float*)d_in[0];   // (8,2048,256)
    const float* adj = (const float*)d_in[1];   // (8,2048,2048)
    const float* W   = (const float*)d_in[2];   // (256,256)
    const float* a   = (const float*)d_in[3];   // (512,1)
    float* out = (float*)d_out;                 // (8,2048,256)

    unsigned short* WhS = (unsigned short*)d_ws;                        // 8.4 MB
    unsigned short* WTs = (unsigned short*)((char*)d_ws + 8388608);     // 128 KB
    float*          s1  = (float*)((char*)d_ws + 8388608 + 131072);     // 64 KB
    float*          s2  = s1 + 16384;                                   // 64 KB

    k_wt  <<<dim3(32),   dim3(256), 0, stream>>>(W, WTs);
    k_wh  <<<dim3(512),  dim3(512), 0, stream>>>(h, WTs, a, WhS, s1, s2);
    k_attn<<<dim3(512),  dim3(512), 0, stream>>>(adj, WhS, s1, s2, out);
}